// Round 10
// baseline (418.870 us; speedup 1.0000x reference)
//
#include <hip/hip_runtime.h>
#include <stdint.h>

// Problem dims (fixed)
constexpr int T_DIM   = 16384;
constexpr int IN_DIM  = 4096;
constexpr int OUT_DIM = 4096;

using int32x4 = __attribute__((ext_vector_type(4))) int;

#define GLOAD_LDS16(g, l)                                                     \
    __builtin_amdgcn_global_load_lds(                                         \
        (const __attribute__((address_space(1))) void*)(uintptr_t)(g),        \
        (__attribute__((address_space(3))) void*)(uintptr_t)(l), 16, 0, 0)

// ===========================================================================
// Pre-pass: int32 (int8-valued) -> packed int8, pre-swizzled for BK=64:
// within each 64-B group of 4 chunks, stored = chunk ^ ((row>>1)&3). (rule #21)
// ===========================================================================
__global__ void pack_swz(const int* __restrict__ src, int8_t* __restrict__ dst,
                         int rows, int cols) {
    int64_t tid = (int64_t)blockIdx.x * blockDim.x + threadIdx.x;
    int64_t nchunks = (int64_t)rows * (cols / 16);
    if (tid >= nchunks) return;
    int row  = (int)(tid / (cols / 16));
    int cidx = (int)(tid % (cols / 16));
    const int32x4* s4 =
        reinterpret_cast<const int32x4*>(src + (int64_t)row * cols + (cidx << 4));
    uint32_t p[4];
#pragma unroll
    for (int v = 0; v < 4; ++v) {
        int32x4 t = s4[v];
        p[v] = (uint32_t)(t[0] & 0xff) | ((uint32_t)(t[1] & 0xff) << 8) |
               ((uint32_t)(t[2] & 0xff) << 16) | ((uint32_t)(t[3] & 0xff) << 24);
    }
    int cs = (cidx & ~3) | ((cidx & 3) ^ ((row >> 1) & 3));
    *reinterpret_cast<int32x4*>(dst + (int64_t)row * cols + (cs << 4)) =
        *reinterpret_cast<int32x4*>(p);
}

// ===========================================================================
// Main GEMM — ROUND 10: occupancy-first geometry.
// R3-R9 proved the 256x256/acc128 structure pins MfmaUtil at 38%: 256-reg
// waves cap the CU at ONE block (2 waves/SIMD), all barrier-locked in the
// same phase, so LDS reads and MFMA bursts serialize (5981cy/tile =
// 2611 MFMA + 2300 LDS + 1100 VALU, back-to-back). Fix = make waves small
// enough for TWO INDEPENDENT blocks/CU (m114: cross-block waves at
// different phases overlap MFMA and LDS pipes fully).
//   tile 256x128, 8 waves (4M x 2N), per-wave 64x64 -> acc[4][4] = 64 AGPR
//   launch_bounds(512,4) -> <=128 regs/wave -> 16 waves/CU = 4/SIMD
//   BK=64: one K-step/tile; per wave: 8 ds_read_b128 + 16 MFMA
//   LDS: 2 x (A 16K + B 8K) = 48 KB -> 2 blocks fit (VGPR-capped at 2)
//   pipeline: stage(t+1)->other buf at tile top; vmcnt(0)+barrier at end
//   (stage issued ~2000cy before the wait -> no stall; proven R9 pattern)
// Same proven MFMA intrinsic, swizzle, C/D layout, epilogue as R2-R9.
// ===========================================================================
constexpr int BM = 256, BN = 128, BK = 64;
constexpr int NT     = IN_DIM / BK;      // 64
constexpr int ATILE  = BM * BK;          // 16 KiB
constexpr int BTILE  = BN * BK;          // 8 KiB
constexpr int BUFSZ  = ATILE + BTILE;    // 24 KiB

__global__ __launch_bounds__(512, 4)
void gemm_i8_oc(const int8_t* __restrict__ x8, const int8_t* __restrict__ w8,
                const int* __restrict__ bias, const float* __restrict__ alphap,
                const float* __restrict__ betap, int* __restrict__ out) {
    __shared__ __align__(16) int8_t lds[2 * BUFSZ];   // 48 KiB

    const int tid  = threadIdx.x;
    const int lane = tid & 63;
    const int wid  = tid >> 6;
    const int wr   = wid >> 1;   // 0..3 (M)
    const int wc   = wid & 1;    // 0..1 (N)

    // XCD-chunked bijective swizzle (nwg = 2048, %8==0)
    const int nwg = gridDim.x;
    const int cpx = nwg >> 3;
    const int bid = blockIdx.x;
    const int swz = (bid & 7) * cpx + (bid >> 3);
    const int bm  = swz >> 5;    // 64 M-blocks
    const int bn  = swz & 31;    // 32 N-blocks
    const int brow = bm * BM;
    const int bcol = bn * BN;

    const float alpha = *alphap;
    const float beta  = *betap;

    const int g = lane >> 4;     // 16B chunk 0..3 within the 64B row
    const int r = lane & 15;

    // ---- staging: 3 moving global pointers (+BK per tile), 3 LDS dests.
    const int offA0 = tid * 16;           // A rows 0..127
    const int offA1 = 8192 + tid * 16;    // A rows 128..255
    const int offB  = tid * 16;           // B rows 0..127
    const int8_t* pA0 = x8 + (int64_t)(brow + (offA0 >> 6)) * IN_DIM + (offA0 & 63);
    const int8_t* pA1 = x8 + (int64_t)(brow + (offA1 >> 6)) * IN_DIM + (offA1 & 63);
    const int8_t* pB0 = w8 + (int64_t)(bcol + (offB  >> 6)) * IN_DIM + (offB  & 63);
    const int dA0 = offA0, dA1 = offA1, dB0 = ATILE + offB;

    // ---- fragment byte-offsets (buffer-invariant; swizzle baked in)
    int aoff[4], boff[4];
#pragma unroll
    for (int m = 0; m < 4; ++m) {
        const int row = wr * 64 + m * 16 + r;
        aoff[m] = row * BK + ((g ^ ((row >> 1) & 3)) << 4);
    }
#pragma unroll
    for (int n = 0; n < 4; ++n) {
        const int row = wc * 64 + n * 16 + r;
        boff[n] = ATILE + row * BK + ((g ^ ((row >> 1) & 3)) << 4);
    }

    int32x4 acc[4][4] = {};

#define STAGE3(DSTB)                                                          \
    do {                                                                      \
        int8_t* nb = lds + (DSTB) * BUFSZ;                                    \
        GLOAD_LDS16(pA0, nb + dA0);                                           \
        GLOAD_LDS16(pA1, nb + dA1);                                           \
        GLOAD_LDS16(pB0, nb + dB0);                                           \
        pA0 += BK; pA1 += BK; pB0 += BK;                                      \
    } while (0)

    // Tile body: stage t+1 -> other buffer, read 8 frags, 16 MFMA, boundary.
#define TILE(RB, SB, PF, LAST)                                                \
    do {                                                                      \
        if (PF) STAGE3(SB);                                                   \
        const int8_t* rb = lds + (RB) * BUFSZ;                                \
        int32x4 af[4], bf[4];                                                 \
        _Pragma("unroll") for (int n = 0; n < 4; ++n)                         \
            bf[n] = *reinterpret_cast<const int32x4*>(rb + boff[n]);          \
        _Pragma("unroll") for (int m = 0; m < 4; ++m)                         \
            af[m] = *reinterpret_cast<const int32x4*>(rb + aoff[m]);          \
        __builtin_amdgcn_s_setprio(1);                                        \
        _Pragma("unroll") for (int m = 0; m < 4; ++m)                         \
            _Pragma("unroll") for (int n = 0; n < 4; ++n)                     \
                acc[m][n] = __builtin_amdgcn_mfma_i32_16x16x64_i8(            \
                    af[m], bf[n], acc[m][n], 0, 0, 0);                        \
        __builtin_amdgcn_s_setprio(0);                                        \
        if (!(LAST)) {                                                        \
            asm volatile("s_waitcnt vmcnt(0)" ::: "memory");                  \
            __builtin_amdgcn_s_barrier();                                     \
            asm volatile("" ::: "memory");                                    \
        }                                                                     \
    } while (0)

    // Prologue: stage tile 0 -> buf0, drain, publish.
    STAGE3(0);
    asm volatile("s_waitcnt vmcnt(0)" ::: "memory");
    __builtin_amdgcn_s_barrier();
    asm volatile("" ::: "memory");

    // Main loop: 2-tile unroll, literal buffer indices. Tiles 0..63.
#pragma unroll 1
    for (int tt = 0; tt < NT - 2; tt += 2) {
        TILE(0, 1, true, false);
        TILE(1, 0, true, false);
    }
    TILE(0, 1, true,  false);   // t = 62, stages tile 63 -> buf1
    TILE(1, 0, false, true);    // t = 63, no stage, no boundary
#undef TILE
#undef STAGE3

    // Epilogue: y = acc*alpha + bias*beta, round, clip, store int32.
    // C/D: col = lane&15, row = (lane>>4)*4 + j.
    const int r4 = (lane >> 4) * 4;
    const int cl = lane & 15;
#pragma unroll
    for (int n = 0; n < 4; ++n) {
        const int col = bcol + wc * 64 + n * 16 + cl;
        const float bterm = (float)bias[col] * beta;
#pragma unroll
        for (int m = 0; m < 4; ++m) {
            const int row0 = brow + wr * 64 + m * 16 + r4;
#pragma unroll
            for (int j = 0; j < 4; ++j) {
                float y = (float)acc[m][n][j] * alpha + bterm;
                y = rintf(y);
                y = fminf(fmaxf(y, -128.0f), 127.0f);
                out[(int64_t)(row0 + j) * OUT_DIM + col] = (int)y;
            }
        }
    }
}

// ===========================================================================
// Fallback (ws too small): reads int32 inputs directly, packs in regs,
// swizzled ds_write. 128x128 tile. Known-correct (round 2). Self-contained.
// ===========================================================================
__global__ __launch_bounds__(256)
void gemm_i8_fb(const int* __restrict__ x32, const int* __restrict__ w32,
                const int* __restrict__ bias, const float* __restrict__ alphap,
                const float* __restrict__ betap, int* __restrict__ out) {
    constexpr int FBM = 128, FBK = 128;
    __shared__ int8_t lA[FBM * FBK];
    __shared__ int8_t lB[FBM * FBK];

    const int tid  = threadIdx.x;
    const int wid  = tid >> 6;
    const int lane = tid & 63;
    const int nwg = gridDim.x;
    const int cpx = nwg >> 3;
    const int bid = blockIdx.x;
    const int swz = (bid & 7) * cpx + (bid >> 3);
    const int brow = (swz >> 5) * FBM;
    const int bcol = (swz & 31) * FBM;
    const int wr = wid >> 1, wc = wid & 1;
    const float alpha = *alphap;
    const float beta  = *betap;

    int32x4 acc[4][4] = {};
    for (int kt = 0; kt < IN_DIM / FBK; ++kt) {
        const int64_t kbase = (int64_t)kt * FBK;
#pragma unroll
        for (int q = 0; q < 4; ++q) {
            const int off = wid * 4096 + q * 1024 + lane * 16;
            const int row = off >> 7;
            const int k   = off & 127;
            const int* ga = x32 + (int64_t)(brow + row) * IN_DIM + kbase + k;
            const int* gb = w32 + (int64_t)(bcol + row) * IN_DIM + kbase + k;
            uint32_t pa[4], pb[4];
#pragma unroll
            for (int v = 0; v < 4; ++v) {
                int32x4 ta = reinterpret_cast<const int32x4*>(ga)[v];
                int32x4 tb = reinterpret_cast<const int32x4*>(gb)[v];
                pa[v] = (uint32_t)(ta[0] & 0xff) | ((uint32_t)(ta[1] & 0xff) << 8) |
                        ((uint32_t)(ta[2] & 0xff) << 16) | ((uint32_t)(ta[3] & 0xff) << 24);
                pb[v] = (uint32_t)(tb[0] & 0xff) | ((uint32_t)(tb[1] & 0xff) << 8) |
                        ((uint32_t)(tb[2] & 0xff) << 16) | ((uint32_t)(tb[3] & 0xff) << 24);
            }
            const int sc = ((k >> 4) ^ (row & 7)) << 4;
            *reinterpret_cast<int32x4*>(lA + row * FBK + sc) = *reinterpret_cast<int32x4*>(pa);
            *reinterpret_cast<int32x4*>(lB + row * FBK + sc) = *reinterpret_cast<int32x4*>(pb);
        }
        __syncthreads();
#pragma unroll
        for (int ks = 0; ks < 2; ++ks) {
            const int gg = lane >> 4, rr = lane & 15;
            const int lc = ks * 4 + gg;
            int32x4 af[4], bf[4];
#pragma unroll
            for (int m = 0; m < 4; ++m) {
                const int row = wr * 64 + m * 16 + rr;
                af[m] = *reinterpret_cast<const int32x4*>(lA + row * FBK + ((lc ^ (row & 7)) << 4));
            }
#pragma unroll
            for (int n = 0; n < 4; ++n) {
                const int row = wc * 64 + n * 16 + rr;
                bf[n] = *reinterpret_cast<const int32x4*>(lB + row * FBK + ((lc ^ (row & 7)) << 4));
            }
#pragma unroll
            for (int m = 0; m < 4; ++m)
#pragma unroll
                for (int n = 0; n < 4; ++n)
                    acc[m][n] = __builtin_amdgcn_mfma_i32_16x16x64_i8(af[m], bf[n], acc[m][n], 0, 0, 0);
        }
        __syncthreads();
    }
    const int r4 = (lane >> 4) * 4;
    const int cl = lane & 15;
#pragma unroll
    for (int n = 0; n < 4; ++n) {
        const int col = bcol + wc * 64 + n * 16 + cl;
        const float bterm = (float)bias[col] * beta;
#pragma unroll
        for (int m = 0; m < 4; ++m) {
            const int row0 = brow + wr * 64 + m * 16 + r4;
#pragma unroll
            for (int j = 0; j < 4; ++j) {
                float y = (float)acc[m][n][j] * alpha + bterm;
                y = rintf(y);
                y = fminf(fmaxf(y, -128.0f), 127.0f);
                out[(int64_t)(row0 + j) * OUT_DIM + col] = (int)y;
            }
        }
    }
}

// ===========================================================================
extern "C" void kernel_launch(void* const* d_in, const int* in_sizes, int n_in,
                              void* d_out, int out_size, void* d_ws, size_t ws_size,
                              hipStream_t stream) {
    const int*   x     = (const int*)d_in[0];
    const int*   w     = (const int*)d_in[1];
    const int*   bias  = (const int*)d_in[2];
    const float* alpha = (const float*)d_in[3];
    const float* beta  = (const float*)d_in[4];
    int*         out   = (int*)d_out;

    const size_t need = (size_t)T_DIM * IN_DIM + (size_t)OUT_DIM * IN_DIM;

    if (ws_size >= need) {
        int8_t* x8 = (int8_t*)d_ws;
        int8_t* w8 = x8 + (size_t)T_DIM * IN_DIM;
        {
            int64_t nch = (int64_t)T_DIM * (IN_DIM / 16);
            pack_swz<<<(int)((nch + 255) / 256), 256, 0, stream>>>(x, x8, T_DIM, IN_DIM);
        }
        {
            int64_t nch = (int64_t)OUT_DIM * (IN_DIM / 16);
            pack_swz<<<(int)((nch + 255) / 256), 256, 0, stream>>>(w, w8, OUT_DIM, IN_DIM);
        }
        const int grid = (T_DIM / BM) * (OUT_DIM / BN);  // 64*32 = 2048
        gemm_i8_oc<<<grid, 512, 0, stream>>>(x8, w8, bias, alpha, beta, out);
    } else {
        const int grid = (T_DIM / 128) * (OUT_DIM / 128);  // 4096
        gemm_i8_fb<<<grid, 256, 0, stream>>>(x, w, bias, alpha, beta, out);
    }
}

// Round 11
// 417.970 us; speedup vs baseline: 1.0022x; 1.0022x over previous
//
#include <hip/hip_runtime.h>
#include <stdint.h>

// Problem dims (fixed)
constexpr int T_DIM   = 16384;
constexpr int IN_DIM  = 4096;
constexpr int OUT_DIM = 4096;

using int32x4 = __attribute__((ext_vector_type(4))) int;

#define GLOAD_LDS16(g, l)                                                     \
    __builtin_amdgcn_global_load_lds(                                         \
        (const __attribute__((address_space(1))) void*)(uintptr_t)(g),        \
        (__attribute__((address_space(3))) void*)(uintptr_t)(l), 16, 0, 0)

// ===========================================================================
// Pre-pass: int32 (int8-valued) -> packed int8, pre-swizzled for BK=64:
// within each 64-B group of 4 chunks, stored = chunk ^ ((row>>1)&3). (rule #21)
// ===========================================================================
__global__ void pack_swz(const int* __restrict__ src, int8_t* __restrict__ dst,
                         int rows, int cols) {
    int64_t tid = (int64_t)blockIdx.x * blockDim.x + threadIdx.x;
    int64_t nchunks = (int64_t)rows * (cols / 16);
    if (tid >= nchunks) return;
    int row  = (int)(tid / (cols / 16));
    int cidx = (int)(tid % (cols / 16));
    const int32x4* s4 =
        reinterpret_cast<const int32x4*>(src + (int64_t)row * cols + (cidx << 4));
    uint32_t p[4];
#pragma unroll
    for (int v = 0; v < 4; ++v) {
        int32x4 t = s4[v];
        p[v] = (uint32_t)(t[0] & 0xff) | ((uint32_t)(t[1] & 0xff) << 8) |
               ((uint32_t)(t[2] & 0xff) << 16) | ((uint32_t)(t[3] & 0xff) << 24);
    }
    int cs = (cidx & ~3) | ((cidx & 3) ^ ((row >> 1) & 3));
    *reinterpret_cast<int32x4*>(dst + (int64_t)row * cols + (cs << 4)) =
        *reinterpret_cast<int32x4*>(p);
}

// ===========================================================================
// Main GEMM — ROUND 10: occupancy-first geometry.
// R3-R9 proved the 256x256/acc128 structure pins MfmaUtil at 38%: 256-reg
// waves cap the CU at ONE block (2 waves/SIMD), all barrier-locked in the
// same phase, so LDS reads and MFMA bursts serialize (5981cy/tile =
// 2611 MFMA + 2300 LDS + 1100 VALU, back-to-back). Fix = make waves small
// enough for TWO INDEPENDENT blocks/CU (m114: cross-block waves at
// different phases overlap MFMA and LDS pipes fully).
//   tile 256x128, 8 waves (4M x 2N), per-wave 64x64 -> acc[4][4] = 64 AGPR
//   launch_bounds(512,4) -> <=128 regs/wave -> 16 waves/CU = 4/SIMD
//   BK=64: one K-step/tile; per wave: 8 ds_read_b128 + 16 MFMA
//   LDS: 2 x (A 16K + B 8K) = 48 KB -> 2 blocks fit (VGPR-capped at 2)
//   pipeline: stage(t+1)->other buf at tile top; vmcnt(0)+barrier at end
//   (stage issued ~2000cy before the wait -> no stall; proven R9 pattern)
// Same proven MFMA intrinsic, swizzle, C/D layout, epilogue as R2-R9.
// ===========================================================================
constexpr int BM = 256, BN = 128, BK = 64;
constexpr int NT     = IN_DIM / BK;      // 64
constexpr int ATILE  = BM * BK;          // 16 KiB
constexpr int BTILE  = BN * BK;          // 8 KiB
constexpr int BUFSZ  = ATILE + BTILE;    // 24 KiB

__global__ __launch_bounds__(512, 4)
void gemm_i8_oc(const int8_t* __restrict__ x8, const int8_t* __restrict__ w8,
                const int* __restrict__ bias, const float* __restrict__ alphap,
                const float* __restrict__ betap, int* __restrict__ out) {
    __shared__ __align__(16) int8_t lds[2 * BUFSZ];   // 48 KiB

    const int tid  = threadIdx.x;
    const int lane = tid & 63;
    const int wid  = tid >> 6;
    const int wr   = wid >> 1;   // 0..3 (M)
    const int wc   = wid & 1;    // 0..1 (N)

    // XCD-chunked bijective swizzle (nwg = 2048, %8==0)
    const int nwg = gridDim.x;
    const int cpx = nwg >> 3;
    const int bid = blockIdx.x;
    const int swz = (bid & 7) * cpx + (bid >> 3);
    const int bm  = swz >> 5;    // 64 M-blocks
    const int bn  = swz & 31;    // 32 N-blocks
    const int brow = bm * BM;
    const int bcol = bn * BN;

    const float alpha = *alphap;
    const float beta  = *betap;

    const int g = lane >> 4;     // 16B chunk 0..3 within the 64B row
    const int r = lane & 15;

    // ---- staging: 3 moving global pointers (+BK per tile), 3 LDS dests.
    const int offA0 = tid * 16;           // A rows 0..127
    const int offA1 = 8192 + tid * 16;    // A rows 128..255
    const int offB  = tid * 16;           // B rows 0..127
    const int8_t* pA0 = x8 + (int64_t)(brow + (offA0 >> 6)) * IN_DIM + (offA0 & 63);
    const int8_t* pA1 = x8 + (int64_t)(brow + (offA1 >> 6)) * IN_DIM + (offA1 & 63);
    const int8_t* pB0 = w8 + (int64_t)(bcol + (offB  >> 6)) * IN_DIM + (offB  & 63);
    const int dA0 = offA0, dA1 = offA1, dB0 = ATILE + offB;

    // ---- fragment byte-offsets (buffer-invariant; swizzle baked in)
    int aoff[4], boff[4];
#pragma unroll
    for (int m = 0; m < 4; ++m) {
        const int row = wr * 64 + m * 16 + r;
        aoff[m] = row * BK + ((g ^ ((row >> 1) & 3)) << 4);
    }
#pragma unroll
    for (int n = 0; n < 4; ++n) {
        const int row = wc * 64 + n * 16 + r;
        boff[n] = ATILE + row * BK + ((g ^ ((row >> 1) & 3)) << 4);
    }

    int32x4 acc[4][4] = {};

#define STAGE3(DSTB)                                                          \
    do {                                                                      \
        int8_t* nb = lds + (DSTB) * BUFSZ;                                    \
        GLOAD_LDS16(pA0, nb + dA0);                                           \
        GLOAD_LDS16(pA1, nb + dA1);                                           \
        GLOAD_LDS16(pB0, nb + dB0);                                           \
        pA0 += BK; pA1 += BK; pB0 += BK;                                      \
    } while (0)

    // Tile body: stage t+1 -> other buffer, read 8 frags, 16 MFMA, boundary.
#define TILE(RB, SB, PF, LAST)                                                \
    do {                                                                      \
        if (PF) STAGE3(SB);                                                   \
        const int8_t* rb = lds + (RB) * BUFSZ;                                \
        int32x4 af[4], bf[4];                                                 \
        _Pragma("unroll") for (int n = 0; n < 4; ++n)                         \
            bf[n] = *reinterpret_cast<const int32x4*>(rb + boff[n]);          \
        _Pragma("unroll") for (int m = 0; m < 4; ++m)                         \
            af[m] = *reinterpret_cast<const int32x4*>(rb + aoff[m]);          \
        __builtin_amdgcn_s_setprio(1);                                        \
        _Pragma("unroll") for (int m = 0; m < 4; ++m)                         \
            _Pragma("unroll") for (int n = 0; n < 4; ++n)                     \
                acc[m][n] = __builtin_amdgcn_mfma_i32_16x16x64_i8(            \
                    af[m], bf[n], acc[m][n], 0, 0, 0);                        \
        __builtin_amdgcn_s_setprio(0);                                        \
        if (!(LAST)) {                                                        \
            asm volatile("s_waitcnt vmcnt(0)" ::: "memory");                  \
            __builtin_amdgcn_s_barrier();                                     \
            asm volatile("" ::: "memory");                                    \
        }                                                                     \
    } while (0)

    // Prologue: stage tile 0 -> buf0, drain, publish.
    STAGE3(0);
    asm volatile("s_waitcnt vmcnt(0)" ::: "memory");
    __builtin_amdgcn_s_barrier();
    asm volatile("" ::: "memory");

    // Main loop: 2-tile unroll, literal buffer indices. Tiles 0..63.
#pragma unroll 1
    for (int tt = 0; tt < NT - 2; tt += 2) {
        TILE(0, 1, true, false);
        TILE(1, 0, true, false);
    }
    TILE(0, 1, true,  false);   // t = 62, stages tile 63 -> buf1
    TILE(1, 0, false, true);    // t = 63, no stage, no boundary
#undef TILE
#undef STAGE3

    // Epilogue: y = acc*alpha + bias*beta, round, clip, store int32.
    // C/D: col = lane&15, row = (lane>>4)*4 + j.
    const int r4 = (lane >> 4) * 4;
    const int cl = lane & 15;
#pragma unroll
    for (int n = 0; n < 4; ++n) {
        const int col = bcol + wc * 64 + n * 16 + cl;
        const float bterm = (float)bias[col] * beta;
#pragma unroll
        for (int m = 0; m < 4; ++m) {
            const int row0 = brow + wr * 64 + m * 16 + r4;
#pragma unroll
            for (int j = 0; j < 4; ++j) {
                float y = (float)acc[m][n][j] * alpha + bterm;
                y = rintf(y);
                y = fminf(fmaxf(y, -128.0f), 127.0f);
                out[(int64_t)(row0 + j) * OUT_DIM + col] = (int)y;
            }
        }
    }
}

// ===========================================================================
// Fallback (ws too small): reads int32 inputs directly, packs in regs,
// swizzled ds_write. 128x128 tile. Known-correct (round 2). Self-contained.
// ===========================================================================
__global__ __launch_bounds__(256)
void gemm_i8_fb(const int* __restrict__ x32, const int* __restrict__ w32,
                const int* __restrict__ bias, const float* __restrict__ alphap,
                const float* __restrict__ betap, int* __restrict__ out) {
    constexpr int FBM = 128, FBK = 128;
    __shared__ int8_t lA[FBM * FBK];
    __shared__ int8_t lB[FBM * FBK];

    const int tid  = threadIdx.x;
    const int wid  = tid >> 6;
    const int lane = tid & 63;
    const int nwg = gridDim.x;
    const int cpx = nwg >> 3;
    const int bid = blockIdx.x;
    const int swz = (bid & 7) * cpx + (bid >> 3);
    const int brow = (swz >> 5) * FBM;
    const int bcol = (swz & 31) * FBM;
    const int wr = wid >> 1, wc = wid & 1;
    const float alpha = *alphap;
    const float beta  = *betap;

    int32x4 acc[4][4] = {};
    for (int kt = 0; kt < IN_DIM / FBK; ++kt) {
        const int64_t kbase = (int64_t)kt * FBK;
#pragma unroll
        for (int q = 0; q < 4; ++q) {
            const int off = wid * 4096 + q * 1024 + lane * 16;
            const int row = off >> 7;
            const int k   = off & 127;
            const int* ga = x32 + (int64_t)(brow + row) * IN_DIM + kbase + k;
            const int* gb = w32 + (int64_t)(bcol + row) * IN_DIM + kbase + k;
            uint32_t pa[4], pb[4];
#pragma unroll
            for (int v = 0; v < 4; ++v) {
                int32x4 ta = reinterpret_cast<const int32x4*>(ga)[v];
                int32x4 tb = reinterpret_cast<const int32x4*>(gb)[v];
                pa[v] = (uint32_t)(ta[0] & 0xff) | ((uint32_t)(ta[1] & 0xff) << 8) |
                        ((uint32_t)(ta[2] & 0xff) << 16) | ((uint32_t)(ta[3] & 0xff) << 24);
                pb[v] = (uint32_t)(tb[0] & 0xff) | ((uint32_t)(tb[1] & 0xff) << 8) |
                        ((uint32_t)(tb[2] & 0xff) << 16) | ((uint32_t)(tb[3] & 0xff) << 24);
            }
            const int sc = ((k >> 4) ^ (row & 7)) << 4;
            *reinterpret_cast<int32x4*>(lA + row * FBK + sc) = *reinterpret_cast<int32x4*>(pa);
            *reinterpret_cast<int32x4*>(lB + row * FBK + sc) = *reinterpret_cast<int32x4*>(pb);
        }
        __syncthreads();
#pragma unroll
        for (int ks = 0; ks < 2; ++ks) {
            const int gg = lane >> 4, rr = lane & 15;
            const int lc = ks * 4 + gg;
            int32x4 af[4], bf[4];
#pragma unroll
            for (int m = 0; m < 4; ++m) {
                const int row = wr * 64 + m * 16 + rr;
                af[m] = *reinterpret_cast<const int32x4*>(lA + row * FBK + ((lc ^ (row & 7)) << 4));
            }
#pragma unroll
            for (int n = 0; n < 4; ++n) {
                const int row = wc * 64 + n * 16 + rr;
                bf[n] = *reinterpret_cast<const int32x4*>(lB + row * FBK + ((lc ^ (row & 7)) << 4));
            }
#pragma unroll
            for (int m = 0; m < 4; ++m)
#pragma unroll
                for (int n = 0; n < 4; ++n)
                    acc[m][n] = __builtin_amdgcn_mfma_i32_16x16x64_i8(af[m], bf[n], acc[m][n], 0, 0, 0);
        }
        __syncthreads();
    }
    const int r4 = (lane >> 4) * 4;
    const int cl = lane & 15;
#pragma unroll
    for (int n = 0; n < 4; ++n) {
        const int col = bcol + wc * 64 + n * 16 + cl;
        const float bterm = (float)bias[col] * beta;
#pragma unroll
        for (int m = 0; m < 4; ++m) {
            const int row0 = brow + wr * 64 + m * 16 + r4;
#pragma unroll
            for (int j = 0; j < 4; ++j) {
                float y = (float)acc[m][n][j] * alpha + bterm;
                y = rintf(y);
                y = fminf(fmaxf(y, -128.0f), 127.0f);
                out[(int64_t)(row0 + j) * OUT_DIM + col] = (int)y;
            }
        }
    }
}

// ===========================================================================
extern "C" void kernel_launch(void* const* d_in, const int* in_sizes, int n_in,
                              void* d_out, int out_size, void* d_ws, size_t ws_size,
                              hipStream_t stream) {
    const int*   x     = (const int*)d_in[0];
    const int*   w     = (const int*)d_in[1];
    const int*   bias  = (const int*)d_in[2];
    const float* alpha = (const float*)d_in[3];
    const float* beta  = (const float*)d_in[4];
    int*         out   = (int*)d_out;

    const size_t need = (size_t)T_DIM * IN_DIM + (size_t)OUT_DIM * IN_DIM;

    if (ws_size >= need) {
        int8_t* x8 = (int8_t*)d_ws;
        int8_t* w8 = x8 + (size_t)T_DIM * IN_DIM;
        {
            int64_t nch = (int64_t)T_DIM * (IN_DIM / 16);
            pack_swz<<<(int)((nch + 255) / 256), 256, 0, stream>>>(x, x8, T_DIM, IN_DIM);
        }
        {
            int64_t nch = (int64_t)OUT_DIM * (IN_DIM / 16);
            pack_swz<<<(int)((nch + 255) / 256), 256, 0, stream>>>(w, w8, OUT_DIM, IN_DIM);
        }
        const int grid = (T_DIM / BM) * (OUT_DIM / BN);  // 64*32 = 2048
        gemm_i8_oc<<<grid, 512, 0, stream>>>(x8, w8, bias, alpha, beta, out);
    } else {
        const int grid = (T_DIM / 128) * (OUT_DIM / 128);  // 4096
        gemm_i8_fb<<<grid, 256, 0, stream>>>(x, w, bias, alpha, beta, out);
    }
}